// Round 11
// baseline (273.167 us; speedup 1.0000x reference)
//
#include <hip/hip_runtime.h>

// VQ-VAE forward: x [64,64,32,32] f32 (NCHW, C==D), weight [512,64] f32.
// d_out: loss (1) | q_out (4194304, NCHW) | encodings (33554432, [N,K]).
//
// R11 = R10 with the main-loop latency fix:
//  - explicit 1-dp frag double-buffer in the dp loop (prefetch dp+1's 8
//    ds_read_b128 before dp's 64 pk_fma; last dp peeled). Operands are LDS
//    (lgkmcnt), cheap to keep in flight — unlike R8's VMEM prefetch.
//  - dropped the cross-compute wstg register prefetch (R10 showed ~0 gain;
//    frees 32 regs for the frag double-buffer). w chunks staged with
//    short-lived regs at chunk boundaries (R9 style).
// Dist arithmetic + tie order bit-identical to R6/R7/R9/R10 (passing):
// even/odd fma chains, (x2+e2)-2dot, per-lane k ascending, strict <,
// explicit lowest-index tie-break in the kg butterfly.

#define NROWS 65536
#define DIM 64
#define KCODES 512
#define HW 1024
#define TPB 256
#define RPB 128                     // rows per block
#define NBLOCKS (NROWS / RPB)       // 512

// d_ws float offsets
#define WT_OFF 0                    // wTp [32 dpair][512 k][2] = 32768 floats
#define E2_OFF 32768                // e2 [512]
#define PART_OFF 98816              // partials [512]

// dynamic LDS float offsets
#define XW 8192                     // xs: 32 dp x 128 rows x (E,O)
#define DYN_FLOATS (XW + 32 * 320)  // + w chunk 32 dp x (16 kg x 20) = 18432
#define DYN_BYTES (DYN_FLOATS * 4)  // 73728 B

typedef float v2f __attribute__((ext_vector_type(2)));
typedef float v4f __attribute__((ext_vector_type(4)));

__global__ __launch_bounds__(256) void vq_prep(
    const float* __restrict__ w, float* __restrict__ ws)
{
    // w -> wTp[dpair][k][2] (E,O interleave) + e2 (ascending-d chain)
    const int k = blockIdx.x * 256 + threadIdx.x;
    float s = 0.0f;
    for (int d = 0; d < DIM; ++d) {
        const float v = w[k * DIM + d];
        ws[WT_OFF + (d >> 1) * (KCODES * 2) + k * 2 + (d & 1)] = v;
        s = __fadd_rn(s, __fmul_rn(v, v));
    }
    ws[E2_OFF + k] = s;
}

__global__ __launch_bounds__(TPB) void vq_main(
    const float* __restrict__ x, const float* __restrict__ w,
    const float* __restrict__ ws, float* __restrict__ out,
    float* __restrict__ partial)
{
    extern __shared__ __align__(16) float smem[];   // [0,XW)=xs, [XW..)=wl
    __shared__ int   idxf[RPB];
    __shared__ float x2l[RPB];
    __shared__ float lred[4];

    const int t    = threadIdx.x;
    const int lane = t & 63;
    const int wv   = __builtin_amdgcn_readfirstlane(t >> 6);
    const int rg   = lane >> 4;       // 0..3: rows wv*32 + rg*8 .. +7
    const int kg   = lane & 15;       // 16 groups x 8 codes per chunk
    const int n0   = blockIdx.x * RPB;
    const int b    = n0 >> 10;        // 1024 % 128 == 0: no b straddle
    const int hw0  = n0 & 1023;

    // ---- stage x tile (128 rows) into LDS, (E,O) interleaved, unpadded:
    // xs[dp*256 + (row>>3)*16 + (row&7)*2 (+1 for odd d)]
    #pragma unroll
    for (int i = 0; i < 4; ++i) {
        const int task = i * 256 + t;          // 1024 tasks
        const int dp   = task >> 5;
        const int row4 = (task & 31) * 4;
        const float* pe = x + (size_t)(b * DIM + 2 * dp) * HW + hw0 + row4;
        const v4f xe = *(const v4f*)pe;        // 4 rows, even depth
        const v4f xo = *(const v4f*)(pe + HW); // 4 rows, odd depth
        float* dst = smem + dp * 256 + (row4 >> 3) * 16 + (row4 & 7) * 2;
        *(v4f*)dst       = (v4f){xe.x, xo.x, xe.y, xo.y};
        *(v4f*)(dst + 4) = (v4f){xe.z, xo.z, xe.w, xo.w};
    }
    __syncthreads();   // xs visible

    // ---- x2 per row from LDS: same ascending-d mul-then-add chain
    if (t < RPB) {
        const float* xb = smem + (t >> 3) * 16 + (t & 7) * 2;
        float s = 0.0f;
        #pragma unroll 8
        for (int dp = 0; dp < 32; ++dp) {
            const v2f p = *(const v2f*)(xb + dp * 256);   // (E,O) of d=2dp
            s = __fadd_rn(s, __fmul_rn(p[0], p[0]));
            s = __fadd_rn(s, __fmul_rn(p[1], p[1]));
        }
        x2l[t] = s;
    }

    const float* e2p = ws + E2_OFF;
    const int cj = wv * 4 + rg;                // x row-chunk id (0..15)
    const int rloc = wv * 32 + rg * 8;         // first row (block-local)

    float best[8];
    int   bidx[8];
    #pragma unroll
    for (int r = 0; r < 8; ++r) { best[r] = 3.4e38f; bidx[r] = 0; }

    float x2v[8];

    // ---- 4 chunks of 128 codes, ascending (=> per-lane k ascending)
    #pragma unroll 1
    for (int c = 0; c < 4; ++c) {
        // stage w chunk c with short-lived regs (not live across compute)
        {
            v4f wtmp[8];
            const float* src = ws + WT_OFF + c * 256;
            #pragma unroll
            for (int i = 0; i < 8; ++i) {
                const int s = i * 1024 + t * 4;
                wtmp[i] = *(const v4f*)(src + (s >> 8) * 1024 + (s & 255));
            }
            // c==0: also covers x2l writes; c>0: prior chunk reads done
            __syncthreads();
            #pragma unroll
            for (int i = 0; i < 8; ++i) {
                const int s   = i * 1024 + t * 4;
                const int dp  = s >> 8;
                const int lc0 = (s & 255) >> 1;
                *(v4f*)(smem + XW + dp * 320 + (lc0 >> 3) * 20
                        + (lc0 & 7) * 2) = wtmp[i];
            }
            __syncthreads();
        }
        if (c == 0) {
            const v4f a = *(const v4f*)(x2l + rloc);
            const v4f bb = *(const v4f*)(x2l + rloc + 4);
            x2v[0]=a.x; x2v[1]=a.y; x2v[2]=a.z; x2v[3]=a.w;
            x2v[4]=bb.x; x2v[5]=bb.y; x2v[6]=bb.z; x2v[7]=bb.w;
        }

        v2f acc[8][8];
        #pragma unroll
        for (int r = 0; r < 8; ++r)
            #pragma unroll
            for (int cc = 0; cc < 8; ++cc) acc[r][cc] = (v2f){0.f, 0.f};

        const float* xp = smem + cj * 16;
        const float* wp = smem + XW + kg * 20;

        // prologue: dp=0 frags
        v4f Xc0 = *(const v4f*)(xp);
        v4f Xc1 = *(const v4f*)(xp + 4);
        v4f Xc2 = *(const v4f*)(xp + 8);
        v4f Xc3 = *(const v4f*)(xp + 12);
        v4f Wc0 = *(const v4f*)(wp);
        v4f Wc1 = *(const v4f*)(wp + 4);
        v4f Wc2 = *(const v4f*)(wp + 8);
        v4f Wc3 = *(const v4f*)(wp + 12);

        #pragma unroll 2
        for (int dp = 0; dp < 31; ++dp) {
            xp += 256;
            wp += 320;
            // prefetch dp+1 (LDS; retires under dp's FMAs)
            const v4f Xn0 = *(const v4f*)(xp);
            const v4f Xn1 = *(const v4f*)(xp + 4);
            const v4f Xn2 = *(const v4f*)(xp + 8);
            const v4f Xn3 = *(const v4f*)(xp + 12);
            const v4f Wn0 = *(const v4f*)(wp);
            const v4f Wn1 = *(const v4f*)(wp + 4);
            const v4f Wn2 = *(const v4f*)(wp + 8);
            const v4f Wn3 = *(const v4f*)(wp + 12);

            const v2f xr[8] = {Xc0.xy, Xc0.zw, Xc1.xy, Xc1.zw,
                               Xc2.xy, Xc2.zw, Xc3.xy, Xc3.zw};
            const v2f wc[8] = {Wc0.xy, Wc0.zw, Wc1.xy, Wc1.zw,
                               Wc2.xy, Wc2.zw, Wc3.xy, Wc3.zw};
            #pragma unroll
            for (int r = 0; r < 8; ++r)
                #pragma unroll
                for (int cc = 0; cc < 8; ++cc)
                    acc[r][cc] += xr[r] * wc[cc];    // v_pk_fma_f32 (E,O)

            Xc0 = Xn0; Xc1 = Xn1; Xc2 = Xn2; Xc3 = Xn3;
            Wc0 = Wn0; Wc1 = Wn1; Wc2 = Wn2; Wc3 = Wn3;
        }
        {   // peeled dp=31
            const v2f xr[8] = {Xc0.xy, Xc0.zw, Xc1.xy, Xc1.zw,
                               Xc2.xy, Xc2.zw, Xc3.xy, Xc3.zw};
            const v2f wc[8] = {Wc0.xy, Wc0.zw, Wc1.xy, Wc1.zw,
                               Wc2.xy, Wc2.zw, Wc3.xy, Wc3.zw};
            #pragma unroll
            for (int r = 0; r < 8; ++r)
                #pragma unroll
                for (int cc = 0; cc < 8; ++cc)
                    acc[r][cc] += xr[r] * wc[cc];
        }

        const int kb = c * 128 + kg * 8;             // lane's 8 codes
        const v4f e20 = *(const v4f*)(e2p + kb);
        const v4f e21 = *(const v4f*)(e2p + kb + 4);
        #pragma unroll
        for (int r = 0; r < 8; ++r) {
            const float x2r = x2v[r];
            #pragma unroll
            for (int cc = 0; cc < 8; ++cc) {         // cc ascending: first-min
                const float dot  = acc[r][cc][0] + acc[r][cc][1];   // E + O
                const float e2c  = (cc < 4) ? e20[cc] : e21[cc - 4];
                const float dist = __fsub_rn(__fadd_rn(x2r, e2c),
                                             __fmul_rn(2.0f, dot));
                if (dist < best[r]) { best[r] = dist; bidx[r] = kb + cc; }
            }
        }
    }

    // ---- kg butterfly (16 lanes); explicit lowest-index tie-break
    #pragma unroll
    for (int m = 1; m <= 8; m <<= 1) {
        #pragma unroll
        for (int r = 0; r < 8; ++r) {
            const float ob = __shfl_xor(best[r], m, 64);
            const int   oi = __shfl_xor(bidx[r], m, 64);
            if (ob < best[r] || (ob == best[r] && oi < bidx[r])) {
                best[r] = ob; bidx[r] = oi;
            }
        }
    }
    if (kg == 0) {
        #pragma unroll
        for (int r = 0; r < 8; ++r)
            idxf[rloc + r] = bidx[r];
    }
    __syncthreads();

    // ---- epilogue: q gather/store + loss; x read from LDS (same values).
    const int rt = t & 127;
    const int dg = t >> 7;            // 2 groups x 32 d (16 dp pairs)
    const int widx = idxf[rt];
    const float* wrow = w + widx * DIM + dg * 32;
    const float* xb = smem + dg * 16 * 256 + (rt >> 3) * 16 + (rt & 7) * 2;
    float* q = out + 1;
    float lsum = 0.0f;
    #pragma unroll
    for (int jj = 0; jj < 16; ++jj) {
        const int dE = dg * 32 + 2 * jj;
        const v2f wp2 = *(const v2f*)(wrow + 2 * jj);     // per-lane, L1-hot
        const v2f xp2 = *(const v2f*)(xb + jj * 256);     // (E,O) from LDS
        const float dfE = __fsub_rn(wp2[0], xp2[0]);      // d ascending: E,O
        lsum = __fadd_rn(lsum, __fmul_rn(dfE, dfE));
        const float dfO = __fsub_rn(wp2[1], xp2[1]);
        lsum = __fadd_rn(lsum, __fmul_rn(dfO, dfO));
        q[(size_t)(b * DIM + dE) * HW + hw0 + rt]     = wp2[0];
        q[(size_t)(b * DIM + dE + 1) * HW + hw0 + rt] = wp2[1];
    }

    #pragma unroll
    for (int off = 32; off; off >>= 1) lsum += __shfl_down(lsum, off, 64);
    if (lane == 0) lred[wv] = lsum;
    __syncthreads();
    if (t == 0)
        partial[blockIdx.x] = (lred[0] + lred[1]) + (lred[2] + lred[3]);

    // ---- encodings: direct compute, aligned float4 middle
    // (slab global float index == 1 mod 4 -> peel 3, tail 1).
    float* slab = out + 1 + (size_t)NROWS * DIM + (size_t)n0 * KCODES;
    if (t < 3) slab[t] = (idxf[0] == t) ? 1.0f : 0.0f;
    if (t == 4) slab[RPB * KCODES - 1] = (idxf[RPB - 1] == 511) ? 1.0f : 0.0f;
    {
        v4f* s4 = (v4f*)(slab + 3);                   // 16B-aligned
        const int nf4 = (RPB * KCODES - 4) / 4;       // 16383
        for (int f = t; f < nf4; f += TPB) {
            const int ii = 3 + 4 * f;
            v4f o;
            #pragma unroll
            for (int cc = 0; cc < 4; ++cc) {
                const int e = ii + cc;
                o[cc] = (idxf[e >> 9] == (e & 511)) ? 1.0f : 0.0f;
            }
            s4[f] = o;
        }
    }
}

__global__ __launch_bounds__(256) void vq_final(
    const float* __restrict__ partial, float* __restrict__ out)
{
    __shared__ float s[256];
    const int t = threadIdx.x;
    s[t] = partial[t] + partial[t + 256];
    __syncthreads();
    for (int off = 128; off; off >>= 1) {
        if (t < off) s[t] += s[t + off];
        __syncthreads();
    }
    if (t == 0) {
        const float m = s[0] / 4194304.0f;            // mean over B*H*W*D
        out[0] = __fadd_rn(m, __fmul_rn(0.25f, m));   // z_q + 0.25*z_e
    }
}

extern "C" void kernel_launch(void* const* d_in, const int* in_sizes, int n_in,
                              void* d_out, int out_size, void* d_ws, size_t ws_size,
                              hipStream_t stream) {
    const float* x = (const float*)d_in[0];
    const float* w = (const float*)d_in[1];
    float* out     = (float*)d_out;
    float* ws      = (float*)d_ws;

    // 73728 B dynamic LDS > 64 KB default limit: opt in (host-side,
    // idempotent, graph-capture-safe — not a stream op).
    (void)hipFuncSetAttribute((const void*)vq_main,
                              hipFuncAttributeMaxDynamicSharedMemorySize,
                              DYN_BYTES);

    vq_prep<<<2, 256, 0, stream>>>(w, ws);
    vq_main<<<NBLOCKS, TPB, DYN_BYTES, stream>>>(x, w, ws, out, ws + PART_OFF);
    vq_final<<<1, 256, 0, stream>>>(ws + PART_OFF, out);
}

// Round 12
// 224.266 us; speedup vs baseline: 1.2181x; 1.2181x over previous
//
#include <hip/hip_runtime.h>

// VQ-VAE forward: x [64,64,32,32] f32 (NCHW, C==D), weight [512,64] f32.
// d_out: loss (1) | q_out (4194304, NCHW) | encodings (33554432, [N,K]).
//
// R12: occupancy + pipe-split fix for R10's DS-bound-at-2-waves/SIMD stall.
//  - w read directly from global wTp (L2-resident 128KB; NO w LDS staging,
//    no per-chunk barriers). x stays in LDS (33KB static -> 4 blocks/CU).
//  - tile 8 rows x 4 codes (acc 64 VGPR, total ~120) -> 3-4 waves/SIMD,
//    12-16 waves/CU (2x R10). DS(x) 41us + TA(w) 27us + VALU 14us now
//    overlap across waves instead of a single starved DS pipe.
//  - NO explicit reg double-buffer (R8/R11 lesson: rotation movs + VGPR
//    pressure lose; compiler's hoist + fine-grained lgkmcnt is better).
// Dist arithmetic + tie order bit-identical to R6/R7/R9/R10 (passing):
// even/odd fma chains, (x2+e2)-2dot, per-lane k ascending (pass-major,
// cc ascending), strict <, explicit lowest-index tie-break in kg butterfly.

#define NROWS 65536
#define DIM 64
#define KCODES 512
#define HW 1024
#define TPB 256
#define RPB 128                     // rows per block
#define NBLOCKS (NROWS / RPB)       // 512

// d_ws float offsets
#define WT_OFF 0                    // wTp [32 dpair][512 k][2] = 32768 floats
#define E2_OFF 32768                // e2 [512]
#define PART_OFF 98816              // partials [512]

typedef float v2f __attribute__((ext_vector_type(2)));
typedef float v4f __attribute__((ext_vector_type(4)));

__global__ __launch_bounds__(256) void vq_prep(
    const float* __restrict__ w, float* __restrict__ ws)
{
    // w -> wTp[dpair][k][2] (E,O interleave) + e2 (ascending-d chain)
    const int k = blockIdx.x * 256 + threadIdx.x;
    float s = 0.0f;
    for (int d = 0; d < DIM; ++d) {
        const float v = w[k * DIM + d];
        ws[WT_OFF + (d >> 1) * (KCODES * 2) + k * 2 + (d & 1)] = v;
        s = __fadd_rn(s, __fmul_rn(v, v));
    }
    ws[E2_OFF + k] = s;
}

__global__ __launch_bounds__(TPB) void vq_main(
    const float* __restrict__ x, const float* __restrict__ w,
    const float* __restrict__ ws, float* __restrict__ out,
    float* __restrict__ partial)
{
    // xs: 32 dp-planes x 128 rows x (E,O) = 8192 floats = 32 KB (unpadded:
    // x-reads are <=2-way bank-aliased = free, m136)
    __shared__ __align__(16) float xs[8192];
    __shared__ int   idxf[RPB];
    __shared__ float x2l[RPB];
    __shared__ float lred[4];

    const int t    = threadIdx.x;
    const int lane = t & 63;
    const int wv   = __builtin_amdgcn_readfirstlane(t >> 6);
    const int rg   = lane >> 4;       // 0..3: rows wv*32 + rg*8 .. +7
    const int kg   = lane & 15;       // 16 groups x 4 codes per pass
    const int n0   = blockIdx.x * RPB;
    const int b    = n0 >> 10;        // 1024 % 128 == 0: no b straddle
    const int hw0  = n0 & 1023;

    // ---- stage x tile (128 rows) into LDS, (E,O) interleaved:
    // xs[dp*256 + (row>>3)*16 + (row&7)*2 (+1 for odd d)]
    #pragma unroll
    for (int i = 0; i < 4; ++i) {
        const int task = i * 256 + t;          // 1024 tasks
        const int dp   = task >> 5;
        const int row4 = (task & 31) * 4;
        const float* pe = x + (size_t)(b * DIM + 2 * dp) * HW + hw0 + row4;
        const v4f xe = *(const v4f*)pe;        // 4 rows, even depth
        const v4f xo = *(const v4f*)(pe + HW); // 4 rows, odd depth
        float* dst = xs + dp * 256 + (row4 >> 3) * 16 + (row4 & 7) * 2;
        *(v4f*)dst       = (v4f){xe.x, xo.x, xe.y, xo.y};
        *(v4f*)(dst + 4) = (v4f){xe.z, xo.z, xe.w, xo.w};
    }
    __syncthreads();   // xs visible

    // ---- x2 per row from LDS: same ascending-d mul-then-add chain
    if (t < RPB) {
        const float* xb = xs + (t >> 3) * 16 + (t & 7) * 2;
        float s = 0.0f;
        #pragma unroll 8
        for (int dp = 0; dp < 32; ++dp) {
            const v2f p = *(const v2f*)(xb + dp * 256);   // (E,O) of d=2dp
            s = __fadd_rn(s, __fmul_rn(p[0], p[0]));
            s = __fadd_rn(s, __fmul_rn(p[1], p[1]));
        }
        x2l[t] = s;
    }
    __syncthreads();   // x2l visible

    const float* e2p = ws + E2_OFF;
    const float* wT  = ws + WT_OFF;
    const int cj   = wv * 4 + rg;              // x row-chunk id (0..15)
    const int rloc = wv * 32 + rg * 8;         // first row (block-local)

    float x2v[8];
    {
        const v4f a  = *(const v4f*)(x2l + rloc);
        const v4f bb = *(const v4f*)(x2l + rloc + 4);
        x2v[0]=a.x; x2v[1]=a.y; x2v[2]=a.z; x2v[3]=a.w;
        x2v[4]=bb.x; x2v[5]=bb.y; x2v[6]=bb.z; x2v[7]=bb.w;
    }

    float best[8];
    int   bidx[8];
    #pragma unroll
    for (int r = 0; r < 8; ++r) { best[r] = 3.4e38f; bidx[r] = 0; }

    // ---- 8 passes of 64 codes, ascending (=> per-lane k ascending).
    // x from LDS, w straight from L2-resident wTp (no LDS staging).
    #pragma unroll 1
    for (int p = 0; p < 8; ++p) {
        const int kb = p * 64 + kg * 4;        // lane's 4 codes this pass
        v2f acc[8][4];
        #pragma unroll
        for (int r = 0; r < 8; ++r)
            #pragma unroll
            for (int cc = 0; cc < 4; ++cc) acc[r][cc] = (v2f){0.f, 0.f};

        const float* xp = xs + cj * 16;
        const float* wp = wT + kb * 2;
        #pragma unroll 4
        for (int dp = 0; dp < 32; ++dp) {
            const v4f X0 = *(const v4f*)(xp);        // rows 0,1 (E,O) pairs
            const v4f X1 = *(const v4f*)(xp + 4);    // rows 2,3
            const v4f X2 = *(const v4f*)(xp + 8);    // rows 4,5
            const v4f X3 = *(const v4f*)(xp + 12);   // rows 6,7
            const v4f W0 = *(const v4f*)(wp);        // codes 0,1 (E,O) pairs
            const v4f W1 = *(const v4f*)(wp + 4);    // codes 2,3
            const v2f xr[8] = {X0.xy, X0.zw, X1.xy, X1.zw,
                               X2.xy, X2.zw, X3.xy, X3.zw};
            const v2f wc[4] = {W0.xy, W0.zw, W1.xy, W1.zw};
            #pragma unroll
            for (int r = 0; r < 8; ++r)
                #pragma unroll
                for (int cc = 0; cc < 4; ++cc)
                    acc[r][cc] += xr[r] * wc[cc];    // v_pk_fma_f32 (E,O)
            xp += 256;
            wp += KCODES * 2;
        }

        const v4f e4 = *(const v4f*)(e2p + kb);      // 4 codes' e2, L1-hot
        #pragma unroll
        for (int r = 0; r < 8; ++r) {
            const float x2r = x2v[r];
            #pragma unroll
            for (int cc = 0; cc < 4; ++cc) {         // cc ascending: first-min
                const float dot  = acc[r][cc][0] + acc[r][cc][1];   // E + O
                const float dist = __fsub_rn(__fadd_rn(x2r, e4[cc]),
                                             __fmul_rn(2.0f, dot));
                if (dist < best[r]) { best[r] = dist; bidx[r] = kb + cc; }
            }
        }
    }

    // ---- kg butterfly (16 lanes); explicit lowest-index tie-break
    #pragma unroll
    for (int m = 1; m <= 8; m <<= 1) {
        #pragma unroll
        for (int r = 0; r < 8; ++r) {
            const float ob = __shfl_xor(best[r], m, 64);
            const int   oi = __shfl_xor(bidx[r], m, 64);
            if (ob < best[r] || (ob == best[r] && oi < bidx[r])) {
                best[r] = ob; bidx[r] = oi;
            }
        }
    }
    if (kg == 0) {
        #pragma unroll
        for (int r = 0; r < 8; ++r)
            idxf[rloc + r] = bidx[r];
    }
    __syncthreads();

    // ---- epilogue: q gather/store + loss; x read from LDS (xs untouched).
    const int rt = t & 127;
    const int dg = t >> 7;            // 2 groups x 32 d (16 dp pairs)
    const int widx = idxf[rt];
    const float* wrow = w + widx * DIM + dg * 32;
    const float* xb = xs + dg * 16 * 256 + (rt >> 3) * 16 + (rt & 7) * 2;
    float* q = out + 1;
    float lsum = 0.0f;
    #pragma unroll
    for (int jj = 0; jj < 16; ++jj) {
        const int dE = dg * 32 + 2 * jj;
        const v2f wp2 = *(const v2f*)(wrow + 2 * jj);     // per-lane, L1-hot
        const v2f xp2 = *(const v2f*)(xb + jj * 256);     // (E,O) from LDS
        const float dfE = __fsub_rn(wp2[0], xp2[0]);      // d ascending: E,O
        lsum = __fadd_rn(lsum, __fmul_rn(dfE, dfE));
        const float dfO = __fsub_rn(wp2[1], xp2[1]);
        lsum = __fadd_rn(lsum, __fmul_rn(dfO, dfO));
        q[(size_t)(b * DIM + dE) * HW + hw0 + rt]     = wp2[0];
        q[(size_t)(b * DIM + dE + 1) * HW + hw0 + rt] = wp2[1];
    }

    #pragma unroll
    for (int off = 32; off; off >>= 1) lsum += __shfl_down(lsum, off, 64);
    if (lane == 0) lred[wv] = lsum;
    __syncthreads();
    if (t == 0)
        partial[blockIdx.x] = (lred[0] + lred[1]) + (lred[2] + lred[3]);

    // ---- encodings: direct compute, aligned float4 middle
    // (slab global float index == 1 mod 4 -> peel 3, tail 1).
    float* slab = out + 1 + (size_t)NROWS * DIM + (size_t)n0 * KCODES;
    if (t < 3) slab[t] = (idxf[0] == t) ? 1.0f : 0.0f;
    if (t == 4) slab[RPB * KCODES - 1] = (idxf[RPB - 1] == 511) ? 1.0f : 0.0f;
    {
        v4f* s4 = (v4f*)(slab + 3);                   // 16B-aligned
        const int nf4 = (RPB * KCODES - 4) / 4;       // 16383
        for (int f = t; f < nf4; f += TPB) {
            const int ii = 3 + 4 * f;
            v4f o;
            #pragma unroll
            for (int cc = 0; cc < 4; ++cc) {
                const int e = ii + cc;
                o[cc] = (idxf[e >> 9] == (e & 511)) ? 1.0f : 0.0f;
            }
            s4[f] = o;
        }
    }
}

__global__ __launch_bounds__(256) void vq_final(
    const float* __restrict__ partial, float* __restrict__ out)
{
    __shared__ float s[256];
    const int t = threadIdx.x;
    s[t] = partial[t] + partial[t + 256];
    __syncthreads();
    for (int off = 128; off; off >>= 1) {
        if (t < off) s[t] += s[t + off];
        __syncthreads();
    }
    if (t == 0) {
        const float m = s[0] / 4194304.0f;            // mean over B*H*W*D
        out[0] = __fadd_rn(m, __fmul_rn(0.25f, m));   // z_q + 0.25*z_e
    }
}

extern "C" void kernel_launch(void* const* d_in, const int* in_sizes, int n_in,
                              void* d_out, int out_size, void* d_ws, size_t ws_size,
                              hipStream_t stream) {
    const float* x = (const float*)d_in[0];
    const float* w = (const float*)d_in[1];
    float* out     = (float*)d_out;
    float* ws      = (float*)d_ws;

    vq_prep<<<2, 256, 0, stream>>>(w, ws);
    vq_main<<<NBLOCKS, TPB, 0, stream>>>(x, w, ws, out, ws + PART_OFF);
    vq_final<<<1, 256, 0, stream>>>(ws + PART_OFF, out);
}